// Round 1
// baseline (2395.522 us; speedup 1.0000x reference)
//
#include <hip/hip_runtime.h>

// ---------------- problem constants ----------------
#define Bb 4
#define Np 4096
#define Ff 6
#define NC 1024
#define NSAMP 64
#define NPTS (Bb*Np)          // 16384 unique points total
// radius^2 exactly as numpy sees it: float32(0.04)
#define R2 ((float)(0.2*0.2))

// ---------------- ws layout (bytes) ----------------
static __host__ __device__ constexpr size_t alup(size_t x){ return (x + 255) & ~(size_t)255; }
// gidx: B*1024*64 ints
static constexpr size_t OFF_GIDX = 0;
static constexpr size_t SZ_GIDX  = (size_t)Bb*NC*NSAMP*4;
// zero zone: mask (B*4096 int) + t1max (B*256 u32) + t2max (B*256 u32)
static constexpr size_t OFF_MASK = alup(OFF_GIDX + SZ_GIDX);
static constexpr size_t SZ_MASK  = (size_t)Bb*Np*4;
static constexpr size_t OFF_T1   = OFF_MASK + SZ_MASK;
static constexpr size_t OFF_T2   = OFF_T1 + (size_t)Bb*256*4;
static constexpr size_t ZERO_BYTES = (OFF_T2 + (size_t)Bb*256*4) - OFF_MASK;
// small tensors
static constexpr size_t OFF_INT  = alup(OFF_T2 + (size_t)Bb*256*4);   // inT ws B*36 f32
static constexpr size_t OFF_FET  = alup(OFF_INT + (size_t)Bb*36*4);   // feT ws B*4096 f32
// activations
static constexpr size_t OFF_XT    = alup(OFF_FET + (size_t)Bb*4096*4);      // [6][16384]
static constexpr size_t OFF_HW    = alup(OFF_XT + (size_t)6*NPTS*4);        // [64][16384]
static constexpr size_t OFF_BUF64 = alup(OFF_HW + (size_t)64*NPTS*4);       // a1/b1/hf  [64][16384]
static constexpr size_t OFF_BUF128= alup(OFF_BUF64 + (size_t)64*NPTS*4);    // a2/b2/c1  [128][16384]
static constexpr size_t OFF_FINAL = alup(OFF_BUF128 + (size_t)128*NPTS*4);  // [16384][256] point-major
static constexpr size_t WS_NEED   = OFF_FINAL + (size_t)NPTS*256*4;

// ---------------- FPS ----------------
// 1 block per batch, 1024 threads, 4 points/thread (strided). Exact np math.
__global__ __launch_bounds__(1024) void fps_kernel(const float* __restrict__ points,
                                                   float* __restrict__ out_cent)
{
    int b = blockIdx.x;
    const float* P = points + (size_t)b * Np * 3;
    int tid = threadIdx.x;
    int wave = tid >> 6;

    float px[4], py[4], pz[4], dist[4];
#pragma unroll
    for (int j = 0; j < 4; ++j) {
        int p = tid + 1024 * j;
        px[j] = P[p*3+0]; py[j] = P[p*3+1]; pz[j] = P[p*3+2];
        dist[j] = 1000000000.0f;
    }

    __shared__ unsigned long long skey[2][16];

    if (tid == 0) {
        out_cent[((size_t)b*NC + 0)*3 + 0] = P[0];
        out_cent[((size_t)b*NC + 0)*3 + 1] = P[1];
        out_cent[((size_t)b*NC + 0)*3 + 2] = P[2];
    }

    int last = 0;
    for (int s = 1; s < NC; ++s) {
        float cx = P[last*3+0], cy = P[last*3+1], cz = P[last*3+2];
        unsigned long long best = 0ull;
#pragma unroll
        for (int j = 0; j < 4; ++j) {
            float dx = __fsub_rn(px[j], cx);
            float dy = __fsub_rn(py[j], cy);
            float dz = __fsub_rn(pz[j], cz);
            float d  = __fadd_rn(__fadd_rn(__fmul_rn(dx,dx), __fmul_rn(dy,dy)), __fmul_rn(dz,dz));
            float nd = fminf(dist[j], d);
            dist[j] = nd;
            unsigned long long key =
                ((unsigned long long)__float_as_uint(nd) << 32) |
                (unsigned)(~(unsigned)(tid + 1024*j));
            best = (key > best) ? key : best;
        }
        // wave reduce (max key)
#pragma unroll
        for (int off = 32; off; off >>= 1) {
            unsigned long long o = __shfl_xor(best, off);
            best = (o > best) ? o : best;
        }
        if ((tid & 63) == 0) skey[s & 1][wave] = best;
        __syncthreads();
        unsigned long long w = skey[s & 1][0];
#pragma unroll
        for (int i = 1; i < 16; ++i) {
            unsigned long long o = skey[s & 1][i];
            w = (o > w) ? o : w;
        }
        int widx = (int)(~(unsigned)(w & 0xFFFFFFFFull));
        last = widx;
        if (tid == 0) {
            out_cent[((size_t)b*NC + s)*3 + 0] = P[widx*3+0];
            out_cent[((size_t)b*NC + s)*3 + 1] = P[widx*3+1];
            out_cent[((size_t)b*NC + s)*3 + 2] = P[widx*3+2];
        }
    }
}

// ---------------- ball query + g_xyz + mask ----------------
// wave per centroid; block = 256 threads = 4 centroids
__global__ __launch_bounds__(256) void ballq_kernel(const float* __restrict__ points,
                                                    const float* __restrict__ cent,
                                                    int* __restrict__ gidx,
                                                    int* __restrict__ mask,
                                                    float* __restrict__ out_gxyz)
{
    int gtid = blockIdx.x * 256 + threadIdx.x;
    int wid  = gtid >> 6;          // b*1024 + c
    int lane = threadIdx.x & 63;
    int b = wid >> 10, c = wid & 1023;
    const float* P = points + (size_t)b * Np * 3;
    float cx = cent[((size_t)b*NC + c)*3 + 0];
    float cy = cent[((size_t)b*NC + c)*3 + 1];
    float cz = cent[((size_t)b*NC + c)*3 + 2];

    __shared__ int sidx[4][NSAMP];
    int* my = sidx[threadIdx.x >> 6];

    int count = 0;
    for (int base = 0; base < Np; base += 64) {
        int p = base + lane;
        float dx = __fsub_rn(cx, P[p*3+0]);
        float dy = __fsub_rn(cy, P[p*3+1]);
        float dz = __fsub_rn(cz, P[p*3+2]);
        float d  = __fadd_rn(__fadd_rn(__fmul_rn(dx,dx), __fmul_rn(dy,dy)), __fmul_rn(dz,dz));
        bool inr = !(d > R2);
        unsigned long long m = __ballot(inr);
        int before = __popcll(m & ((1ull << lane) - 1ull));
        int pos = count + before;
        if (inr && pos < NSAMP) my[pos] = p;
        count += (int)__popcll(m);
        if (count >= NSAMP) break;
    }
    __syncthreads();
    int total = count < NSAMP ? count : NSAMP;
    int first = my[0];
    int myi = (lane < total) ? my[lane] : first;
    gidx[(size_t)wid * NSAMP + lane] = myi;
    mask[(size_t)b * Np + myi] = 1;
    float qx = P[myi*3+0], qy = P[myi*3+1], qz = P[myi*3+2];
    out_gxyz[(((size_t)b*3 + 0)*NC + c)*NSAMP + lane] = __fsub_rn(qx, cx);
    out_gxyz[(((size_t)b*3 + 1)*NC + c)*NSAMP + lane] = __fsub_rn(qy, cy);
    out_gxyz[(((size_t)b*3 + 2)*NC + c)*NSAMP + lane] = __fsub_rn(qz, cz);
}

// ---------------- x transpose to channel-major ----------------
__global__ __launch_bounds__(256) void xpose_kernel(const float* __restrict__ x, float* __restrict__ xT)
{
    int id = blockIdx.x * 256 + threadIdx.x;   // id over 6*16384
    if (id < Ff * NPTS) {
        int ch = id >> 14;     // /16384
        int g  = id & (NPTS-1);
        xT[id] = x[(size_t)g * Ff + ch];
    }
}

// ---------------- generic layer: out = [relu](in @ W) ----------------
// in: [K][16384] channel-major. W: [K][N] (+ optional per-batch stride). out: channel-major or point-major.
template<int K, int N, bool RELU, bool PM>
__global__ __launch_bounds__(64) void layer_k(const float* __restrict__ in,
                                              const float* __restrict__ W, int wBStride,
                                              float* __restrict__ out)
{
    int lane = threadIdx.x;
    int g = blockIdx.x * 64 + lane;
    int b = g >> 12;
    const float* Wb = W + (size_t)b * wBStride;
    float a[K];
#pragma unroll
    for (int k = 0; k < K; ++k) a[k] = in[(size_t)k * NPTS + g];
    int per = N / gridDim.y;
    int o0 = blockIdx.y * per;
    for (int o = o0; o < o0 + per; ++o) {
        float acc = 0.f;
#pragma unroll
        for (int k = 0; k < K; ++k) acc += a[k] * Wb[(size_t)k * N + o];
        if (RELU) acc = fmaxf(acc, 0.f);
        if (PM) out[(size_t)g * N + o] = acc;
        else    out[(size_t)o * NPTS + g] = acc;
    }
}

// ---------------- layer + masked per-channel max (into global atomics) ----------------
template<int K, int N>
__global__ __launch_bounds__(64) void layer_max_k(const float* __restrict__ in,
                                                  const float* __restrict__ W,
                                                  const int* __restrict__ mask,
                                                  unsigned* __restrict__ tmax)
{
    int lane = threadIdx.x;
    int g = blockIdx.x * 64 + lane;
    int b = g >> 12;
    float a[K];
#pragma unroll
    for (int k = 0; k < K; ++k) a[k] = in[(size_t)k * NPTS + g];
    bool present = mask[g] != 0;
    int per = N / gridDim.y;
    int o0 = blockIdx.y * per;
    for (int o = o0; o < o0 + per; ++o) {
        float acc = 0.f;
#pragma unroll
        for (int k = 0; k < K; ++k) acc += a[k] * W[(size_t)k * N + o];
        float v = present ? fmaxf(acc, 0.f) : 0.f;
#pragma unroll
        for (int off = 32; off; off >>= 1) v = fmaxf(v, __shfl_xor(v, off));
        if (lane == 0) atomicMax(&tmax[(size_t)b * N + o], __float_as_uint(v));
    }
}

// ---------------- h = relu((x @ inT) @ w1) ----------------
__global__ __launch_bounds__(64) void l_h_kernel(const float* __restrict__ xT,
                                                 const float* __restrict__ inT,
                                                 const float* __restrict__ w1,
                                                 float* __restrict__ hw)
{
    int g = blockIdx.x * 64 + threadIdx.x;
    int b = g >> 12;
    float v[6];
#pragma unroll
    for (int c = 0; c < 6; ++c) v[c] = xT[(size_t)c * NPTS + g];
    float t[6];
#pragma unroll
    for (int o = 0; o < 6; ++o) {
        float acc = 0.f;
#pragma unroll
        for (int c = 0; c < 6; ++c) acc += v[c] * inT[b*36 + c*6 + o];
        t[o] = acc;
    }
    for (int j = 0; j < 64; ++j) {
        float acc = 0.f;
#pragma unroll
        for (int o = 0; o < 6; ++o) acc += t[o] * w1[o*64 + j];
        hw[(size_t)j * NPTS + g] = fmaxf(acc, 0.f);
    }
}

// ---------------- tnet heads ----------------
__global__ __launch_bounds__(256) void head1_kernel(const unsigned* __restrict__ t1,
                                                    const float* __restrict__ f1,  // 256x128
                                                    const float* __restrict__ f2,  // 128x36
                                                    float* __restrict__ outT, float* __restrict__ wsT)
{
    int b = blockIdx.x, t = threadIdx.x;
    __shared__ float tv[256], u[128];
    tv[t] = __uint_as_float(t1[(size_t)b*256 + t]);
    __syncthreads();
    if (t < 128) {
        float acc = 0.f;
        for (int k = 0; k < 256; ++k) acc += tv[k] * f1[(size_t)k*128 + t];
        u[t] = fmaxf(acc, 0.f);
    }
    __syncthreads();
    if (t < 36) {
        float acc = 0.f;
        for (int k = 0; k < 128; ++k) acc += u[k] * f2[(size_t)k*36 + t];
        if (t / 6 == t % 6) acc += 1.0f;
        outT[b*36 + t] = acc;
        wsT[b*36 + t]  = acc;
    }
}

__global__ __launch_bounds__(256) void head2_kernel(const unsigned* __restrict__ t2,
                                                    const float* __restrict__ f1,  // 256x128
                                                    const float* __restrict__ f2,  // 128x4096
                                                    float* __restrict__ outT, float* __restrict__ wsT)
{
    int b = blockIdx.x, t = threadIdx.x;
    __shared__ float tv[256], u[128];
    tv[t] = __uint_as_float(t2[(size_t)b*256 + t]);
    __syncthreads();
    if (t < 128) {
        float acc = 0.f;
        for (int k = 0; k < 256; ++k) acc += tv[k] * f1[(size_t)k*128 + t];
        u[t] = fmaxf(acc, 0.f);
    }
    __syncthreads();
    for (int j = t; j < 4096; j += 256) {
        float acc = 0.f;
        for (int k = 0; k < 128; ++k) acc += u[k] * f2[(size_t)k*4096 + j];
        if (j / 64 == j % 64) acc += 1.0f;
        outT[(size_t)b*4096 + j] = acc;
        wsT[(size_t)b*4096 + j]  = acc;
    }
}

// ---------------- feats: grouped gather-max + transpose ----------------
__global__ __launch_bounds__(256) void feats_kernel(const float* __restrict__ fin,   // [16384][256] point-major
                                                    const int* __restrict__ gidx,
                                                    float* __restrict__ out)         // (B,256,1024)
{
    int bid = blockIdx.x;            // b*1024 + c
    int b = bid >> 10, c = bid & 1023;
    int o = threadIdx.x;
    __shared__ int sid[NSAMP];
    if (o < NSAMP) sid[o] = gidx[(size_t)bid * NSAMP + o];
    __syncthreads();
    const float* fb = fin + (size_t)b * Np * 256;
    float m = -1e30f;
    for (int s = 0; s < NSAMP; ++s)
        m = fmaxf(m, fb[(size_t)sid[s] * 256 + o]);
    out[((size_t)b*256 + o)*NC + c] = m;
}

// ---------------- launch ----------------
extern "C" void kernel_launch(void* const* d_in, const int* in_sizes, int n_in,
                              void* d_out, int out_size, void* d_ws, size_t ws_size,
                              hipStream_t stream)
{
    const float* x      = (const float*)d_in[0];
    const float* points = (const float*)d_in[1];
    const float* t1_w1  = (const float*)d_in[2];
    const float* t1_w2  = (const float*)d_in[3];
    const float* t1_w3  = (const float*)d_in[4];
    const float* t1_f1  = (const float*)d_in[5];
    const float* t1_f2  = (const float*)d_in[6];
    const float* t2_w1  = (const float*)d_in[7];
    const float* t2_w2  = (const float*)d_in[8];
    const float* t2_w3  = (const float*)d_in[9];
    const float* t2_f1  = (const float*)d_in[10];
    const float* t2_f2  = (const float*)d_in[11];
    const float* w1     = (const float*)d_in[12];
    const float* w2     = (const float*)d_in[13];
    const float* w3     = (const float*)d_in[14];

    float* out = (float*)d_out;
    float* out_cent  = out;                 // (4,1024,3)
    float* out_gxyz  = out + 12288;         // (4,3,1024,64)
    float* out_feats = out + 798720;        // (4,256,1024)
    float* out_inT   = out + 1847296;       // (4,6,6)
    float* out_feT   = out + 1847440;       // (4,64,64)

    char* ws = (char*)d_ws;
    int*      gidx  = (int*)(ws + OFF_GIDX);
    int*      mask  = (int*)(ws + OFF_MASK);
    unsigned* t1max = (unsigned*)(ws + OFF_T1);
    unsigned* t2max = (unsigned*)(ws + OFF_T2);
    float*    wsInT = (float*)(ws + OFF_INT);
    float*    wsFeT = (float*)(ws + OFF_FET);
    float*    xT    = (float*)(ws + OFF_XT);
    float*    hw    = (float*)(ws + OFF_HW);
    float*    buf64 = (float*)(ws + OFF_BUF64);    // a1 / b1 / hf
    float*    buf128= (float*)(ws + OFF_BUF128);   // a2 / b2 / c1
    float*    fin   = (float*)(ws + OFF_FINAL);    // [16384][256]

    // zero mask + tnet maxima
    hipMemsetAsync(ws + OFF_MASK, 0, ZERO_BYTES, stream);

    // 1. FPS -> centroids (exact)
    fps_kernel<<<Bb, 1024, 0, stream>>>(points, out_cent);
    // 2. ball query -> gidx, mask, g_xyz output (exact)
    ballq_kernel<<<(Bb*NC)/4, 256, 0, stream>>>(points, out_cent, gidx, mask, out_gxyz);
    // 3. x -> channel-major
    xpose_kernel<<<(Ff*NPTS + 255)/256, 256, 0, stream>>>(x, xT);

    dim3 lgrid(NPTS/64, 4);
    // tnet1 trunk
    layer_k<6, 64, true, false><<<lgrid, 64, 0, stream>>>(xT, t1_w1, 0, buf64);          // a1
    layer_k<64,128, true, false><<<lgrid, 64, 0, stream>>>(buf64, t1_w2, 0, buf128);     // a2
    layer_max_k<128,256><<<lgrid, 64, 0, stream>>>(buf128, t1_w3, mask, t1max);          // t1
    head1_kernel<<<Bb, 256, 0, stream>>>(t1max, t1_f1, t1_f2, out_inT, wsInT);           // inT
    // h = relu((x @ inT) @ w1)
    l_h_kernel<<<NPTS/64, 64, 0, stream>>>(xT, wsInT, w1, hw);
    // tnet2 trunk
    layer_k<64, 64, true, false><<<lgrid, 64, 0, stream>>>(hw, t2_w1, 0, buf64);         // b1
    layer_k<64,128, true, false><<<lgrid, 64, 0, stream>>>(buf64, t2_w2, 0, buf128);     // b2
    layer_max_k<128,256><<<lgrid, 64, 0, stream>>>(buf128, t2_w3, mask, t2max);          // t2
    head2_kernel<<<Bb, 256, 0, stream>>>(t2max, t2_f1, t2_f2, out_feT, wsFeT);           // feT
    // hf = h @ feT (no relu, per-batch weight)
    layer_k<64, 64, false, false><<<lgrid, 64, 0, stream>>>(hw, wsFeT, 4096, buf64);     // hf
    // c1 = relu(hf @ w2)
    layer_k<64,128, true, false><<<lgrid, 64, 0, stream>>>(buf64, w2, 0, buf128);        // c1
    // final = relu(c1 @ w3), point-major
    layer_k<128,256, true, true><<<lgrid, 64, 0, stream>>>(buf128, w3, 0, fin);          // final
    // feats gather-max
    feats_kernel<<<Bb*NC, 256, 0, stream>>>(fin, gidx, out_feats);

    (void)in_sizes; (void)n_in; (void)out_size; (void)ws_size;
}

// Round 2
// 1091.110 us; speedup vs baseline: 2.1955x; 2.1955x over previous
//
#include <hip/hip_runtime.h>

// ---------------- problem constants ----------------
#define Bb 4
#define Np 4096
#define Ff 6
#define NC 1024
#define NSAMP 64
#define NPTS (Bb*Np)          // 16384 unique points total
// radius^2 exactly as numpy sees it: float32(0.04)
#define R2 ((float)(0.2*0.2))

// ---------------- ws layout (bytes) ----------------
static __host__ __device__ constexpr size_t alup(size_t x){ return (x + 255) & ~(size_t)255; }
static constexpr size_t OFF_GIDX = 0;
static constexpr size_t SZ_GIDX  = (size_t)Bb*NC*NSAMP*4;
static constexpr size_t OFF_MASK = alup(OFF_GIDX + SZ_GIDX);
static constexpr size_t SZ_MASK  = (size_t)Bb*Np*4;
static constexpr size_t OFF_T1   = OFF_MASK + SZ_MASK;        // t1 max  B*256 f32
static constexpr size_t OFF_T2   = OFF_T1 + (size_t)Bb*256*4; // t2 max  B*256 f32
static constexpr size_t OFF_INT  = alup(OFF_T2 + (size_t)Bb*256*4);   // inT ws B*36 f32
static constexpr size_t OFF_FET  = alup(OFF_INT + (size_t)Bb*36*4);   // feT ws B*4096 f32
static constexpr size_t OFF_XT    = alup(OFF_FET + (size_t)Bb*4096*4);      // [6][16384]
static constexpr size_t OFF_HW    = alup(OFF_XT + (size_t)6*NPTS*4);        // [64][16384]
static constexpr size_t OFF_BUF64 = alup(OFF_HW + (size_t)64*NPTS*4);       // a1/b1/hf  [64][16384]
static constexpr size_t OFF_BUF128= alup(OFF_BUF64 + (size_t)64*NPTS*4);    // a2/b2/c1  [128][16384]
static constexpr size_t OFF_FINAL = alup(OFF_BUF128 + (size_t)128*NPTS*4);  // 16MB: t-layer out (cm) / final (pm)

// ---------------- FPS ----------------
// 1 block per batch, 512 threads (8 waves), 8 points/thread. Exact np math.
// Per step: local dist update + (m,jsel) track, key=(distbits<<32)|~idx as double,
// 6-level wave fmax-reduce, lane0 -> LDS, barrier, replicated 8-key reduce (3 lvls),
// coords via ds_read_b128 broadcast from LDS float4 table.
__global__ __launch_bounds__(512) void fps_kernel(const float* __restrict__ points,
                                                  float* __restrict__ out_cent)
{
    int b = blockIdx.x;
    const float* P = points + (size_t)b * Np * 3;
    int tid  = threadIdx.x;
    int lane = tid & 63;
    int wave = tid >> 6;

    __shared__ float4 sc[Np];            // 64 KB coord table
    __shared__ double skey[2][8];

    float px[8], py[8], pz[8], dist[8];
#pragma unroll
    for (int j = 0; j < 8; ++j) {
        int p = tid + 512 * j;
        float x = P[p*3+0], y = P[p*3+1], z = P[p*3+2];
        px[j] = x; py[j] = y; pz[j] = z;
        dist[j] = 1000000000.0f;
        sc[p] = make_float4(x, y, z, 0.f);
    }
    __syncthreads();

    float cx = sc[0].x, cy = sc[0].y, cz = sc[0].z;
    if (tid == 0) {
        out_cent[((size_t)b*NC + 0)*3 + 0] = cx;
        out_cent[((size_t)b*NC + 0)*3 + 1] = cy;
        out_cent[((size_t)b*NC + 0)*3 + 2] = cz;
    }

    for (int s = 1; s < NC; ++s) {
        float m = -1.0f;
        int jsel = 0;
#pragma unroll
        for (int j = 0; j < 8; ++j) {
            float dx = __fsub_rn(px[j], cx);
            float dy = __fsub_rn(py[j], cy);
            float dz = __fsub_rn(pz[j], cz);
            float d  = __fadd_rn(__fadd_rn(__fmul_rn(dx,dx), __fmul_rn(dy,dy)), __fmul_rn(dz,dz));
            float nd = fminf(dist[j], d);
            dist[j] = nd;
            bool gt = nd > m;          // strict >, ascending j => first occurrence in lane
            jsel = gt ? j : jsel;
            m    = gt ? nd : m;
        }
        unsigned idx = (unsigned)tid + ((unsigned)jsel << 9);   // global point index
        double key = __hiloint2double(__float_as_int(m), (int)~idx);
        // keys are positive-bit-pattern doubles -> v_max_f64 == u64 max
#pragma unroll
        for (int off = 1; off < 64; off <<= 1)
            key = fmax(key, __shfl_xor(key, off));
        if (lane == 0) skey[s & 1][wave] = key;
        __syncthreads();
        double kk = skey[s & 1][lane & 7];
#pragma unroll
        for (int off = 1; off < 8; off <<= 1)
            kk = fmax(kk, __shfl_xor(kk, off));
        int widx = (int)(~(unsigned)__double2loint(kk));
        float4 c = sc[widx];
        cx = c.x; cy = c.y; cz = c.z;
        if (tid == 0) {
            out_cent[((size_t)b*NC + s)*3 + 0] = cx;
            out_cent[((size_t)b*NC + s)*3 + 1] = cy;
            out_cent[((size_t)b*NC + s)*3 + 2] = cz;
        }
    }
}

// ---------------- ball query + g_xyz + mask ----------------
__global__ __launch_bounds__(256) void ballq_kernel(const float* __restrict__ points,
                                                    const float* __restrict__ cent,
                                                    int* __restrict__ gidx,
                                                    int* __restrict__ mask,
                                                    float* __restrict__ out_gxyz)
{
    int gtid = blockIdx.x * 256 + threadIdx.x;
    int wid  = gtid >> 6;          // b*1024 + c
    int lane = threadIdx.x & 63;
    int b = wid >> 10, c = wid & 1023;
    const float* P = points + (size_t)b * Np * 3;
    float cx = cent[((size_t)b*NC + c)*3 + 0];
    float cy = cent[((size_t)b*NC + c)*3 + 1];
    float cz = cent[((size_t)b*NC + c)*3 + 2];

    __shared__ int sidx[4][NSAMP];
    int* my = sidx[threadIdx.x >> 6];

    int count = 0;
    for (int base = 0; base < Np; base += 64) {
        int p = base + lane;
        float dx = __fsub_rn(cx, P[p*3+0]);
        float dy = __fsub_rn(cy, P[p*3+1]);
        float dz = __fsub_rn(cz, P[p*3+2]);
        float d  = __fadd_rn(__fadd_rn(__fmul_rn(dx,dx), __fmul_rn(dy,dy)), __fmul_rn(dz,dz));
        bool inr = !(d > R2);
        unsigned long long mball = __ballot(inr);
        int before = __popcll(mball & ((1ull << lane) - 1ull));
        int pos = count + before;
        if (inr && pos < NSAMP) my[pos] = p;
        count += (int)__popcll(mball);
        if (count >= NSAMP) break;
    }
    __syncthreads();
    int total = count < NSAMP ? count : NSAMP;
    int first = my[0];
    int myi = (lane < total) ? my[lane] : first;
    gidx[(size_t)wid * NSAMP + lane] = myi;
    mask[(size_t)b * Np + myi] = 1;
    float qx = P[myi*3+0], qy = P[myi*3+1], qz = P[myi*3+2];
    out_gxyz[(((size_t)b*3 + 0)*NC + c)*NSAMP + lane] = __fsub_rn(qx, cx);
    out_gxyz[(((size_t)b*3 + 1)*NC + c)*NSAMP + lane] = __fsub_rn(qy, cy);
    out_gxyz[(((size_t)b*3 + 2)*NC + c)*NSAMP + lane] = __fsub_rn(qz, cz);
}

// ---------------- x transpose to channel-major ----------------
__global__ __launch_bounds__(256) void xpose_kernel(const float* __restrict__ x, float* __restrict__ xT)
{
    int id = blockIdx.x * 256 + threadIdx.x;   // over 6*16384
    if (id < Ff * NPTS) {
        int ch = id >> 14;
        int g  = id & (NPTS-1);
        xT[id] = x[(size_t)g * Ff + ch];
    }
}

// ---------------- register-blocked layer: out = [relu](in @ W) ----------------
// in: [K][16384] channel-major. W: [K][N] (row-major; per-batch stride K*N if BW).
// block = 256 threads; tile = 1024 points x NT outputs; MT=4 points/thread.
// grid = (16, N/NT).
template<int K, int N, int NT, bool RELU, bool PM, bool BW>
__global__ __launch_bounds__(256) void layer2_k(const float* __restrict__ in,
                                                const float* __restrict__ W,
                                                float* __restrict__ out)
{
    int tid = threadIdx.x;
    int g0  = blockIdx.x * 1024 + tid;
    int o0  = blockIdx.y * NT;
    const float* Wb = W;
    if (BW) Wb += (size_t)(blockIdx.x >> 2) * K * N;

    __shared__ float ws[K * NT];
    for (int i = tid; i < K * NT; i += 256)
        ws[i] = Wb[(size_t)(i / NT) * N + o0 + (i % NT)];
    __syncthreads();

    float acc[4][NT];
#pragma unroll
    for (int mi = 0; mi < 4; ++mi)
#pragma unroll
        for (int oo = 0; oo < NT; ++oo) acc[mi][oo] = 0.f;

#pragma unroll 4
    for (int k = 0; k < K; ++k) {
        float a0 = in[(size_t)k * NPTS + g0];
        float a1 = in[(size_t)k * NPTS + g0 + 256];
        float a2 = in[(size_t)k * NPTS + g0 + 512];
        float a3 = in[(size_t)k * NPTS + g0 + 768];
#pragma unroll
        for (int oo = 0; oo < NT; ++oo) {
            float w = ws[k * NT + oo];
            acc[0][oo] += a0 * w;
            acc[1][oo] += a1 * w;
            acc[2][oo] += a2 * w;
            acc[3][oo] += a3 * w;
        }
    }

#pragma unroll
    for (int mi = 0; mi < 4; ++mi) {
        int g = g0 + mi * 256;
#pragma unroll
        for (int oo = 0; oo < NT; ++oo) {
            float v = acc[mi][oo];
            if (RELU) v = fmaxf(v, 0.f);
            if (PM) out[(size_t)g * N + o0 + oo] = v;
            else    out[(size_t)(o0 + oo) * NPTS + g] = v;
        }
    }
}

// ---------------- masked per-(b,ch) max of relu over points ----------------
// buf: [256][16384] channel-major. grid = Bb*256 blocks of 256 threads.
__global__ __launch_bounds__(256) void maxmask_kernel(const float* __restrict__ buf,
                                                      const int* __restrict__ mask,
                                                      float* __restrict__ tmax)
{
    int bid = blockIdx.x;
    int b = bid >> 8, ch = bid & 255;
    int tid = threadIdx.x;
    const float* row = buf + (size_t)ch * NPTS + (size_t)b * Np;
    const int* mk = mask + (size_t)b * Np;
    float m = 0.f;
#pragma unroll
    for (int i = 0; i < Np / 256; ++i) {
        int p = tid + i * 256;
        float v = row[p];
        if (mk[p]) m = fmaxf(m, fmaxf(v, 0.f));
    }
#pragma unroll
    for (int off = 1; off < 64; off <<= 1)
        m = fmaxf(m, __shfl_xor(m, off));
    __shared__ float red[4];
    if ((tid & 63) == 0) red[tid >> 6] = m;
    __syncthreads();
    if (tid == 0) {
        float r = fmaxf(fmaxf(red[0], red[1]), fmaxf(red[2], red[3]));
        tmax[(size_t)b * 256 + ch] = r;
    }
}

// ---------------- h = relu((x @ inT) @ w1) ----------------
__global__ __launch_bounds__(256) void l_h_kernel(const float* __restrict__ xT,
                                                  const float* __restrict__ inT,
                                                  const float* __restrict__ w1,
                                                  float* __restrict__ hw)
{
    int g = blockIdx.x * 256 + threadIdx.x;
    int b = g >> 12;
    float v[6];
#pragma unroll
    for (int c = 0; c < 6; ++c) v[c] = xT[(size_t)c * NPTS + g];
    float t[6];
#pragma unroll
    for (int o = 0; o < 6; ++o) {
        float acc = 0.f;
#pragma unroll
        for (int c = 0; c < 6; ++c) acc += v[c] * inT[b*36 + c*6 + o];
        t[o] = acc;
    }
#pragma unroll 8
    for (int j = 0; j < 64; ++j) {
        float acc = 0.f;
#pragma unroll
        for (int o = 0; o < 6; ++o) acc += t[o] * w1[o*64 + j];
        hw[(size_t)j * NPTS + g] = fmaxf(acc, 0.f);
    }
}

// ---------------- tnet heads ----------------
__global__ __launch_bounds__(256) void head1_kernel(const float* __restrict__ t1,
                                                    const float* __restrict__ f1,  // 256x128
                                                    const float* __restrict__ f2,  // 128x36
                                                    float* __restrict__ outT, float* __restrict__ wsT)
{
    int b = blockIdx.x, t = threadIdx.x;
    __shared__ float tv[256], u[128];
    tv[t] = t1[(size_t)b*256 + t];
    __syncthreads();
    if (t < 128) {
        float acc = 0.f;
        for (int k = 0; k < 256; ++k) acc += tv[k] * f1[(size_t)k*128 + t];
        u[t] = fmaxf(acc, 0.f);
    }
    __syncthreads();
    if (t < 36) {
        float acc = 0.f;
        for (int k = 0; k < 128; ++k) acc += u[k] * f2[(size_t)k*36 + t];
        if (t / 6 == t % 6) acc += 1.0f;
        outT[b*36 + t] = acc;
        wsT[b*36 + t]  = acc;
    }
}

// grid (Bb, 16): each block computes u[128] (redundant, tiny) then 256 j-outputs.
__global__ __launch_bounds__(256) void head2_kernel(const float* __restrict__ t2,
                                                    const float* __restrict__ f1,  // 256x128
                                                    const float* __restrict__ f2,  // 128x4096
                                                    float* __restrict__ outT, float* __restrict__ wsT)
{
    int b = blockIdx.x, t = threadIdx.x;
    __shared__ float tv[256], u[128];
    tv[t] = t2[(size_t)b*256 + t];
    __syncthreads();
    if (t < 128) {
        float acc = 0.f;
        for (int k = 0; k < 256; ++k) acc += tv[k] * f1[(size_t)k*128 + t];
        u[t] = fmaxf(acc, 0.f);
    }
    __syncthreads();
    int j = blockIdx.y * 256 + t;
    float acc = 0.f;
#pragma unroll 8
    for (int k = 0; k < 128; ++k) acc += u[k] * f2[(size_t)k*4096 + j];
    if (j / 64 == j % 64) acc += 1.0f;
    outT[(size_t)b*4096 + j] = acc;
    wsT[(size_t)b*4096 + j]  = acc;
}

// ---------------- feats: grouped gather-max + transpose ----------------
__global__ __launch_bounds__(256) void feats_kernel(const float* __restrict__ fin,   // [16384][256] pm
                                                    const int* __restrict__ gidx,
                                                    float* __restrict__ out)         // (B,256,1024)
{
    int bid = blockIdx.x;            // b*1024 + c
    int b = bid >> 10, c = bid & 1023;
    int o = threadIdx.x;
    __shared__ int sid[NSAMP];
    if (o < NSAMP) sid[o] = gidx[(size_t)bid * NSAMP + o];
    __syncthreads();
    const float* fb = fin + (size_t)b * Np * 256;
    float m = -1e30f;
    for (int s = 0; s < NSAMP; ++s)
        m = fmaxf(m, fb[(size_t)sid[s] * 256 + o]);
    out[((size_t)b*256 + o)*NC + c] = m;
}

// ---------------- launch ----------------
extern "C" void kernel_launch(void* const* d_in, const int* in_sizes, int n_in,
                              void* d_out, int out_size, void* d_ws, size_t ws_size,
                              hipStream_t stream)
{
    const float* x      = (const float*)d_in[0];
    const float* points = (const float*)d_in[1];
    const float* t1_w1  = (const float*)d_in[2];
    const float* t1_w2  = (const float*)d_in[3];
    const float* t1_w3  = (const float*)d_in[4];
    const float* t1_f1  = (const float*)d_in[5];
    const float* t1_f2  = (const float*)d_in[6];
    const float* t2_w1  = (const float*)d_in[7];
    const float* t2_w2  = (const float*)d_in[8];
    const float* t2_w3  = (const float*)d_in[9];
    const float* t2_f1  = (const float*)d_in[10];
    const float* t2_f2  = (const float*)d_in[11];
    const float* w1     = (const float*)d_in[12];
    const float* w2     = (const float*)d_in[13];
    const float* w3     = (const float*)d_in[14];

    float* out = (float*)d_out;
    float* out_cent  = out;                 // (4,1024,3)
    float* out_gxyz  = out + 12288;         // (4,3,1024,64)
    float* out_feats = out + 798720;        // (4,256,1024)
    float* out_inT   = out + 1847296;       // (4,6,6)
    float* out_feT   = out + 1847440;       // (4,64,64)

    char* ws = (char*)d_ws;
    int*   gidx  = (int*)(ws + OFF_GIDX);
    int*   mask  = (int*)(ws + OFF_MASK);
    float* t1max = (float*)(ws + OFF_T1);
    float* t2max = (float*)(ws + OFF_T2);
    float* wsInT = (float*)(ws + OFF_INT);
    float* wsFeT = (float*)(ws + OFF_FET);
    float* xT    = (float*)(ws + OFF_XT);
    float* hw    = (float*)(ws + OFF_HW);
    float* buf64 = (float*)(ws + OFF_BUF64);
    float* buf128= (float*)(ws + OFF_BUF128);
    float* fin   = (float*)(ws + OFF_FINAL);

    hipMemsetAsync(ws + OFF_MASK, 0, SZ_MASK, stream);

    fps_kernel<<<Bb, 512, 0, stream>>>(points, out_cent);
    ballq_kernel<<<(Bb*NC)/4, 256, 0, stream>>>(points, out_cent, gidx, mask, out_gxyz);
    xpose_kernel<<<(Ff*NPTS + 255)/256, 256, 0, stream>>>(x, xT);

    // tnet1 trunk
    layer2_k<6,  64, 16, true,  false, false><<<dim3(16, 4), 256, 0, stream>>>(xT,    t1_w1, buf64);
    layer2_k<64, 128,16, true,  false, false><<<dim3(16, 8), 256, 0, stream>>>(buf64, t1_w2, buf128);
    layer2_k<128,256,16, false, false, false><<<dim3(16,16), 256, 0, stream>>>(buf128,t1_w3, fin);
    maxmask_kernel<<<Bb*256, 256, 0, stream>>>(fin, mask, t1max);
    head1_kernel<<<Bb, 256, 0, stream>>>(t1max, t1_f1, t1_f2, out_inT, wsInT);
    // h = relu((x @ inT) @ w1)
    l_h_kernel<<<NPTS/256, 256, 0, stream>>>(xT, wsInT, w1, hw);
    // tnet2 trunk
    layer2_k<64, 64, 16, true,  false, false><<<dim3(16, 4), 256, 0, stream>>>(hw,    t2_w1, buf64);
    layer2_k<64, 128,16, true,  false, false><<<dim3(16, 8), 256, 0, stream>>>(buf64, t2_w2, buf128);
    layer2_k<128,256,16, false, false, false><<<dim3(16,16), 256, 0, stream>>>(buf128,t2_w3, fin);
    maxmask_kernel<<<Bb*256, 256, 0, stream>>>(fin, mask, t2max);
    head2_kernel<<<dim3(Bb,16), 256, 0, stream>>>(t2max, t2_f1, t2_f2, out_feT, wsFeT);
    // hf = h @ feT (per-batch weights)
    layer2_k<64, 64, 16, false, false, true ><<<dim3(16, 4), 256, 0, stream>>>(hw,    wsFeT, buf64);
    // c1 = relu(hf @ w2)
    layer2_k<64, 128,16, true,  false, false><<<dim3(16, 8), 256, 0, stream>>>(buf64, w2,    buf128);
    // final = relu(c1 @ w3), point-major
    layer2_k<128,256,16, true,  true,  false><<<dim3(16,16), 256, 0, stream>>>(buf128,w3,    fin);
    feats_kernel<<<Bb*NC, 256, 0, stream>>>(fin, gidx, out_feats);

    (void)in_sizes; (void)n_in; (void)out_size; (void)ws_size;
}

// Round 3
// 920.047 us; speedup vs baseline: 2.6037x; 1.1859x over previous
//
#include <hip/hip_runtime.h>

// ---------------- problem constants ----------------
#define Bb 4
#define Np 4096
#define Ff 6
#define NC 1024
#define NSAMP 64
#define NPTS (Bb*Np)          // 16384 unique points total
// radius^2 exactly as numpy sees it: float32(0.04)
#define R2 ((float)(0.2*0.2))

// ---------------- ws layout (bytes) ----------------
static __host__ __device__ constexpr size_t alup(size_t x){ return (x + 255) & ~(size_t)255; }
static constexpr size_t OFF_GIDX = 0;
static constexpr size_t SZ_GIDX  = (size_t)Bb*NC*NSAMP*4;
static constexpr size_t OFF_MASK = alup(OFF_GIDX + SZ_GIDX);
static constexpr size_t SZ_MASK  = (size_t)Bb*Np*4;
static constexpr size_t OFF_T1   = OFF_MASK + SZ_MASK;        // t1 max  B*256 f32 (atomic, zero-init)
static constexpr size_t OFF_T2   = OFF_T1 + (size_t)Bb*256*4; // t2 max  B*256 f32 (atomic, zero-init)
static constexpr size_t ZERO_BYTES = (OFF_T2 + (size_t)Bb*256*4) - OFF_MASK;
static constexpr size_t OFF_INT  = alup(OFF_T2 + (size_t)Bb*256*4);   // inT ws B*36 f32
static constexpr size_t OFF_FET  = alup(OFF_INT + (size_t)Bb*36*4);   // feT ws B*4096 f32
static constexpr size_t OFF_XT    = alup(OFF_FET + (size_t)Bb*4096*4);      // [6][16384]
static constexpr size_t OFF_HW    = alup(OFF_XT + (size_t)6*NPTS*4);        // [64][16384]
static constexpr size_t OFF_BUF64 = alup(OFF_HW + (size_t)64*NPTS*4);       // a1/b1/hf  [64][16384]
static constexpr size_t OFF_BUF128= alup(OFF_BUF64 + (size_t)64*NPTS*4);    // a2/b2/c1  [128][16384]
static constexpr size_t OFF_FINAL = alup(OFF_BUF128 + (size_t)128*NPTS*4);  // final (pm) [16384][256]

// ---------------- DPP full-wave u32 max; result valid in lane 63 ----------------
// row_shr:1,2,4,8 then row_bcast:15, row_bcast:31. bound_ctrl=false + old=v =>
// lanes with invalid source keep their own value (identity for max).
__device__ __forceinline__ unsigned wave_red_umax(unsigned v)
{
#define DPP_STEP(ctrl) { unsigned t = (unsigned)__builtin_amdgcn_update_dpp((int)v, (int)v, ctrl, 0xF, 0xF, false); v = (t > v) ? t : v; }
    DPP_STEP(0x111)  // row_shr:1
    DPP_STEP(0x112)  // row_shr:2
    DPP_STEP(0x114)  // row_shr:4
    DPP_STEP(0x118)  // row_shr:8
    DPP_STEP(0x142)  // row_bcast:15
    DPP_STEP(0x143)  // row_bcast:31
#undef DPP_STEP
    return v;        // lane 63 holds the full-wave max
}

// ---------------- FPS ----------------
// 1 block per batch, 512 threads (8 waves), 8 points/thread. Exact np math.
// Per step: dist update + running max (1 v_max), post-loop first-occurrence index,
// two-phase DPP reduce (dist bits then ~idx), lane63 -> LDS pair, barrier,
// 2x ds_read_b128 broadcast + 7 fmax_f64 tree, coord broadcast from LDS float4 table.
__global__ __launch_bounds__(512) void fps_kernel(const float* __restrict__ points,
                                                  float* __restrict__ out_cent)
{
    int b = blockIdx.x;
    const float* P = points + (size_t)b * Np * 3;
    int tid  = threadIdx.x;
    int lane = tid & 63;
    int wave = tid >> 6;

    __shared__ float4 sc[Np];                    // 64 KB coord table
    __shared__ __align__(16) uint2 swin[2][8];   // per-wave (dist_bits, ~idx)

    float px[8], py[8], pz[8], dist[8];
#pragma unroll
    for (int j = 0; j < 8; ++j) {
        int p = tid + 512 * j;
        float x = P[p*3+0], y = P[p*3+1], z = P[p*3+2];
        px[j] = x; py[j] = y; pz[j] = z;
        dist[j] = 1000000000.0f;
        sc[p] = make_float4(x, y, z, 0.f);
    }
    __syncthreads();

    float cx = sc[0].x, cy = sc[0].y, cz = sc[0].z;
    if (tid == 0) {
        out_cent[((size_t)b*NC + 0)*3 + 0] = cx;
        out_cent[((size_t)b*NC + 0)*3 + 1] = cy;
        out_cent[((size_t)b*NC + 0)*3 + 2] = cz;
    }

    for (int s = 1; s < NC; ++s) {
        float m = -1.0f;
#pragma unroll
        for (int j = 0; j < 8; ++j) {
            float dx = __fsub_rn(px[j], cx);
            float dy = __fsub_rn(py[j], cy);
            float dz = __fsub_rn(pz[j], cz);
            float d  = __fadd_rn(__fadd_rn(__fmul_rn(dx,dx), __fmul_rn(dy,dy)), __fmul_rn(dz,dz));
            float nd = fminf(dist[j], d);
            dist[j] = nd;
            m = fmaxf(m, nd);
        }
        // first-occurrence (smallest point index) within lane: smallest j matching m
        unsigned pi = 0u;
#pragma unroll
        for (int j = 7; j >= 0; --j)
            pi = (dist[j] == m) ? (unsigned)(tid + (j << 9)) : pi;

        unsigned mb = __float_as_uint(m);              // m >= 0 -> u32-monotone
        unsigned mr = wave_red_umax(mb);
        unsigned maxd = (unsigned)__builtin_amdgcn_readlane((int)mr, 63);
        unsigned cand = (mb == maxd) ? ~pi : 0u;       // max ~pi == min pi
        unsigned cr = wave_red_umax(cand);
        if (lane == 63) swin[s & 1][wave] = make_uint2(mr, cr);
        __syncthreads();

        const uint4* sw = (const uint4*)&swin[s & 1][0];
        uint4 q0 = sw[0], q1 = sw[1], q2 = sw[2], q3 = sw[3];
        // positive doubles compare like u64: (dist<<32)|~idx
        double k0 = fmax(__hiloint2double((int)q0.x, (int)q0.y), __hiloint2double((int)q0.z, (int)q0.w));
        double k1 = fmax(__hiloint2double((int)q1.x, (int)q1.y), __hiloint2double((int)q1.z, (int)q1.w));
        double k2 = fmax(__hiloint2double((int)q2.x, (int)q2.y), __hiloint2double((int)q2.z, (int)q2.w));
        double k3 = fmax(__hiloint2double((int)q3.x, (int)q3.y), __hiloint2double((int)q3.z, (int)q3.w));
        double kk = fmax(fmax(k0, k1), fmax(k2, k3));
        int widx = (int)(~(unsigned)__double2loint(kk));

        float4 c = sc[widx];
        cx = c.x; cy = c.y; cz = c.z;
        if (tid == 0) {
            out_cent[((size_t)b*NC + s)*3 + 0] = cx;
            out_cent[((size_t)b*NC + s)*3 + 1] = cy;
            out_cent[((size_t)b*NC + s)*3 + 2] = cz;
        }
    }
}

// ---------------- ball query + g_xyz + mask ----------------
__global__ __launch_bounds__(256) void ballq_kernel(const float* __restrict__ points,
                                                    const float* __restrict__ cent,
                                                    int* __restrict__ gidx,
                                                    int* __restrict__ mask,
                                                    float* __restrict__ out_gxyz)
{
    int gtid = blockIdx.x * 256 + threadIdx.x;
    int wid  = gtid >> 6;          // b*1024 + c
    int lane = threadIdx.x & 63;
    int b = wid >> 10, c = wid & 1023;
    const float* P = points + (size_t)b * Np * 3;
    float cx = cent[((size_t)b*NC + c)*3 + 0];
    float cy = cent[((size_t)b*NC + c)*3 + 1];
    float cz = cent[((size_t)b*NC + c)*3 + 2];

    __shared__ int sidx[4][NSAMP];
    int* my = sidx[threadIdx.x >> 6];

    int count = 0;
    for (int base = 0; base < Np; base += 64) {
        int p = base + lane;
        float dx = __fsub_rn(cx, P[p*3+0]);
        float dy = __fsub_rn(cy, P[p*3+1]);
        float dz = __fsub_rn(cz, P[p*3+2]);
        float d  = __fadd_rn(__fadd_rn(__fmul_rn(dx,dx), __fmul_rn(dy,dy)), __fmul_rn(dz,dz));
        bool inr = !(d > R2);
        unsigned long long mball = __ballot(inr);
        int before = __popcll(mball & ((1ull << lane) - 1ull));
        int pos = count + before;
        if (inr && pos < NSAMP) my[pos] = p;
        count += (int)__popcll(mball);
        if (count >= NSAMP) break;
    }
    __syncthreads();
    int total = count < NSAMP ? count : NSAMP;
    int first = my[0];
    int myi = (lane < total) ? my[lane] : first;
    gidx[(size_t)wid * NSAMP + lane] = myi;
    mask[(size_t)b * Np + myi] = 1;
    float qx = P[myi*3+0], qy = P[myi*3+1], qz = P[myi*3+2];
    out_gxyz[(((size_t)b*3 + 0)*NC + c)*NSAMP + lane] = __fsub_rn(qx, cx);
    out_gxyz[(((size_t)b*3 + 1)*NC + c)*NSAMP + lane] = __fsub_rn(qy, cy);
    out_gxyz[(((size_t)b*3 + 2)*NC + c)*NSAMP + lane] = __fsub_rn(qz, cz);
}

// ---------------- x transpose to channel-major ----------------
__global__ __launch_bounds__(256) void xpose_kernel(const float* __restrict__ x, float* __restrict__ xT)
{
    int id = blockIdx.x * 256 + threadIdx.x;   // over 6*16384
    if (id < Ff * NPTS) {
        int ch = id >> 14;
        int g  = id & (NPTS-1);
        xT[id] = x[(size_t)g * Ff + ch];
    }
}

// ---------------- register-blocked layer: out = [relu](in @ W) ----------------
// in: [K][16384] channel-major. W: [K][N] (row-major; per-batch stride K*N if BW).
// block = 256 threads; tile = 1024 points x NT outputs; 4 points/thread.
// grid = (16, N/NT).
// TM mode (trunk layer-3): no output write; masked relu-max per channel ->
// global atomicMax into tmax[b*256 + o] (nonneg floats as u32). Requires N==256.
template<int K, int N, int NT, bool RELU, bool PM, bool BW, bool TM>
__global__ __launch_bounds__(256) void layer2_k(const float* __restrict__ in,
                                                const float* __restrict__ W,
                                                float* __restrict__ out,
                                                const int* __restrict__ mask,
                                                unsigned* __restrict__ tmax)
{
    int tid = threadIdx.x;
    int g0  = blockIdx.x * 1024 + tid;
    int o0  = blockIdx.y * NT;
    const float* Wb = W;
    if (BW) Wb += (size_t)(blockIdx.x >> 2) * K * N;

    __shared__ float ws[K * NT];
    for (int i = tid; i < K * NT; i += 256)
        ws[i] = Wb[(size_t)(i / NT) * N + o0 + (i % NT)];
    __syncthreads();

    float acc[4][NT];
#pragma unroll
    for (int mi = 0; mi < 4; ++mi)
#pragma unroll
        for (int oo = 0; oo < NT; ++oo) acc[mi][oo] = 0.f;

#pragma unroll 4
    for (int k = 0; k < K; ++k) {
        float a0 = in[(size_t)k * NPTS + g0];
        float a1 = in[(size_t)k * NPTS + g0 + 256];
        float a2 = in[(size_t)k * NPTS + g0 + 512];
        float a3 = in[(size_t)k * NPTS + g0 + 768];
#pragma unroll
        for (int oo = 0; oo < NT; ++oo) {
            float w = ws[k * NT + oo];
            acc[0][oo] += a0 * w;
            acc[1][oo] += a1 * w;
            acc[2][oo] += a2 * w;
            acc[3][oo] += a3 * w;
        }
    }

    if (TM) {
        float tmv[NT];
#pragma unroll
        for (int oo = 0; oo < NT; ++oo) tmv[oo] = 0.f;
#pragma unroll
        for (int mi = 0; mi < 4; ++mi) {
            bool pres = mask[g0 + mi * 256] != 0;
#pragma unroll
            for (int oo = 0; oo < NT; ++oo) {
                float v = pres ? fmaxf(acc[mi][oo], 0.f) : 0.f;
                tmv[oo] = fmaxf(tmv[oo], v);
            }
        }
        int b = g0 >> 12;
        int lane = tid & 63;
#pragma unroll
        for (int oo = 0; oo < NT; ++oo) {
            unsigned r = wave_red_umax(__float_as_uint(tmv[oo]));
            if (lane == 63)
                atomicMax(&tmax[(b << 8) + o0 + oo], r);
        }
        return;
    }

#pragma unroll
    for (int mi = 0; mi < 4; ++mi) {
        int g = g0 + mi * 256;
#pragma unroll
        for (int oo = 0; oo < NT; ++oo) {
            float v = acc[mi][oo];
            if (RELU) v = fmaxf(v, 0.f);
            if (PM) out[(size_t)g * N + o0 + oo] = v;
            else    out[(size_t)(o0 + oo) * NPTS + g] = v;
        }
    }
}

// ---------------- h = relu((x @ inT) @ w1) ----------------
__global__ __launch_bounds__(256) void l_h_kernel(const float* __restrict__ xT,
                                                  const float* __restrict__ inT,
                                                  const float* __restrict__ w1,
                                                  float* __restrict__ hw)
{
    int g = blockIdx.x * 256 + threadIdx.x;
    int b = g >> 12;
    float v[6];
#pragma unroll
    for (int c = 0; c < 6; ++c) v[c] = xT[(size_t)c * NPTS + g];
    float t[6];
#pragma unroll
    for (int o = 0; o < 6; ++o) {
        float acc = 0.f;
#pragma unroll
        for (int c = 0; c < 6; ++c) acc += v[c] * inT[b*36 + c*6 + o];
        t[o] = acc;
    }
#pragma unroll 8
    for (int j = 0; j < 64; ++j) {
        float acc = 0.f;
#pragma unroll
        for (int o = 0; o < 6; ++o) acc += t[o] * w1[o*64 + j];
        hw[(size_t)j * NPTS + g] = fmaxf(acc, 0.f);
    }
}

// ---------------- tnet heads ----------------
__global__ __launch_bounds__(256) void head1_kernel(const float* __restrict__ t1,
                                                    const float* __restrict__ f1,  // 256x128
                                                    const float* __restrict__ f2,  // 128x36
                                                    float* __restrict__ outT, float* __restrict__ wsT)
{
    int b = blockIdx.x, t = threadIdx.x;
    __shared__ float tv[256], u[128];
    tv[t] = t1[(size_t)b*256 + t];
    __syncthreads();
    if (t < 128) {
        float acc = 0.f;
        for (int k = 0; k < 256; ++k) acc += tv[k] * f1[(size_t)k*128 + t];
        u[t] = fmaxf(acc, 0.f);
    }
    __syncthreads();
    if (t < 36) {
        float acc = 0.f;
        for (int k = 0; k < 128; ++k) acc += u[k] * f2[(size_t)k*36 + t];
        if (t / 6 == t % 6) acc += 1.0f;
        outT[b*36 + t] = acc;
        wsT[b*36 + t]  = acc;
    }
}

// grid (Bb, 16): each block computes u[128] (redundant, tiny) then 256 j-outputs.
__global__ __launch_bounds__(256) void head2_kernel(const float* __restrict__ t2,
                                                    const float* __restrict__ f1,  // 256x128
                                                    const float* __restrict__ f2,  // 128x4096
                                                    float* __restrict__ outT, float* __restrict__ wsT)
{
    int b = blockIdx.x, t = threadIdx.x;
    __shared__ float tv[256], u[128];
    tv[t] = t2[(size_t)b*256 + t];
    __syncthreads();
    if (t < 128) {
        float acc = 0.f;
        for (int k = 0; k < 256; ++k) acc += tv[k] * f1[(size_t)k*128 + t];
        u[t] = fmaxf(acc, 0.f);
    }
    __syncthreads();
    int j = blockIdx.y * 256 + t;
    float acc = 0.f;
#pragma unroll 8
    for (int k = 0; k < 128; ++k) acc += u[k] * f2[(size_t)k*4096 + j];
    if (j / 64 == j % 64) acc += 1.0f;
    outT[(size_t)b*4096 + j] = acc;
    wsT[(size_t)b*4096 + j]  = acc;
}

// ---------------- feats: grouped gather-max + transpose ----------------
__global__ __launch_bounds__(256) void feats_kernel(const float* __restrict__ fin,   // [16384][256] pm
                                                    const int* __restrict__ gidx,
                                                    float* __restrict__ out)         // (B,256,1024)
{
    int bid = blockIdx.x;            // b*1024 + c
    int b = bid >> 10, c = bid & 1023;
    int o = threadIdx.x;
    __shared__ int sid[NSAMP];
    if (o < NSAMP) sid[o] = gidx[(size_t)bid * NSAMP + o];
    __syncthreads();
    const float* fb = fin + (size_t)b * Np * 256;
    float m = -1e30f;
    for (int s = 0; s < NSAMP; ++s)
        m = fmaxf(m, fb[(size_t)sid[s] * 256 + o]);
    out[((size_t)b*256 + o)*NC + c] = m;
}

// ---------------- launch ----------------
extern "C" void kernel_launch(void* const* d_in, const int* in_sizes, int n_in,
                              void* d_out, int out_size, void* d_ws, size_t ws_size,
                              hipStream_t stream)
{
    const float* x      = (const float*)d_in[0];
    const float* points = (const float*)d_in[1];
    const float* t1_w1  = (const float*)d_in[2];
    const float* t1_w2  = (const float*)d_in[3];
    const float* t1_w3  = (const float*)d_in[4];
    const float* t1_f1  = (const float*)d_in[5];
    const float* t1_f2  = (const float*)d_in[6];
    const float* t2_w1  = (const float*)d_in[7];
    const float* t2_w2  = (const float*)d_in[8];
    const float* t2_w3  = (const float*)d_in[9];
    const float* t2_f1  = (const float*)d_in[10];
    const float* t2_f2  = (const float*)d_in[11];
    const float* w1     = (const float*)d_in[12];
    const float* w2     = (const float*)d_in[13];
    const float* w3     = (const float*)d_in[14];

    float* out = (float*)d_out;
    float* out_cent  = out;                 // (4,1024,3)
    float* out_gxyz  = out + 12288;         // (4,3,1024,64)
    float* out_feats = out + 798720;        // (4,256,1024)
    float* out_inT   = out + 1847296;       // (4,6,6)
    float* out_feT   = out + 1847440;       // (4,64,64)

    char* ws = (char*)d_ws;
    int*      gidx  = (int*)(ws + OFF_GIDX);
    int*      mask  = (int*)(ws + OFF_MASK);
    unsigned* t1max = (unsigned*)(ws + OFF_T1);
    unsigned* t2max = (unsigned*)(ws + OFF_T2);
    float*    wsInT = (float*)(ws + OFF_INT);
    float*    wsFeT = (float*)(ws + OFF_FET);
    float*    xT    = (float*)(ws + OFF_XT);
    float*    hw    = (float*)(ws + OFF_HW);
    float*    buf64 = (float*)(ws + OFF_BUF64);
    float*    buf128= (float*)(ws + OFF_BUF128);
    float*    fin   = (float*)(ws + OFF_FINAL);

    // zero mask + t1max + t2max (contiguous)
    hipMemsetAsync(ws + OFF_MASK, 0, ZERO_BYTES, stream);

    fps_kernel<<<Bb, 512, 0, stream>>>(points, out_cent);
    ballq_kernel<<<(Bb*NC)/4, 256, 0, stream>>>(points, out_cent, gidx, mask, out_gxyz);
    xpose_kernel<<<(Ff*NPTS + 255)/256, 256, 0, stream>>>(x, xT);

    // tnet1 trunk (layer3 fused with masked max)
    layer2_k<6,  64, 16, true,  false, false, false><<<dim3(16, 4), 256, 0, stream>>>(xT,    t1_w1, buf64,  nullptr, nullptr);
    layer2_k<64, 128,16, true,  false, false, false><<<dim3(16, 8), 256, 0, stream>>>(buf64, t1_w2, buf128, nullptr, nullptr);
    layer2_k<128,256,16, false, false, false, true ><<<dim3(16,16), 256, 0, stream>>>(buf128,t1_w3, nullptr, mask, t1max);
    head1_kernel<<<Bb, 256, 0, stream>>>((const float*)t1max, t1_f1, t1_f2, out_inT, wsInT);
    // h = relu((x @ inT) @ w1)
    l_h_kernel<<<NPTS/256, 256, 0, stream>>>(xT, wsInT, w1, hw);
    // tnet2 trunk (layer3 fused with masked max)
    layer2_k<64, 64, 16, true,  false, false, false><<<dim3(16, 4), 256, 0, stream>>>(hw,    t2_w1, buf64,  nullptr, nullptr);
    layer2_k<64, 128,16, true,  false, false, false><<<dim3(16, 8), 256, 0, stream>>>(buf64, t2_w2, buf128, nullptr, nullptr);
    layer2_k<128,256,16, false, false, false, true ><<<dim3(16,16), 256, 0, stream>>>(buf128,t2_w3, nullptr, mask, t2max);
    head2_kernel<<<dim3(Bb,16), 256, 0, stream>>>((const float*)t2max, t2_f1, t2_f2, out_feT, wsFeT);
    // hf = h @ feT (per-batch weights)
    layer2_k<64, 64, 16, false, false, true,  false><<<dim3(16, 4), 256, 0, stream>>>(hw,    wsFeT, buf64,  nullptr, nullptr);
    // c1 = relu(hf @ w2)
    layer2_k<64, 128,16, true,  false, false, false><<<dim3(16, 8), 256, 0, stream>>>(buf64, w2,    buf128, nullptr, nullptr);
    // final = relu(c1 @ w3), point-major
    layer2_k<128,256,16, true,  true,  false, false><<<dim3(16,16), 256, 0, stream>>>(buf128,w3,    fin,    nullptr, nullptr);
    feats_kernel<<<Bb*NC, 256, 0, stream>>>(fin, gidx, out_feats);

    (void)in_sizes; (void)n_in; (void)out_size; (void)ws_size;
}

// Round 5
// 791.110 us; speedup vs baseline: 3.0281x; 1.1630x over previous
//
#include <hip/hip_runtime.h>

// ---------------- problem constants ----------------
#define Bb 4
#define Np 4096
#define Ff 6
#define NC 1024
#define NSAMP 64
#define NPTS (Bb*Np)          // 16384 unique points total
// radius^2 exactly as numpy sees it: float32(0.04)
#define R2 ((float)(0.2*0.2))

// ---------------- ws layout (bytes) ----------------
static __host__ __device__ constexpr size_t alup(size_t x){ return (x + 255) & ~(size_t)255; }
static constexpr size_t OFF_GIDX = 0;
static constexpr size_t SZ_GIDX  = (size_t)Bb*NC*NSAMP*4;
static constexpr size_t OFF_MASK = alup(OFF_GIDX + SZ_GIDX);
static constexpr size_t SZ_MASK  = (size_t)Bb*Np*4;
static constexpr size_t OFF_T1   = OFF_MASK + SZ_MASK;        // t1 max  B*256 f32 (atomic, zero-init)
static constexpr size_t OFF_T2   = OFF_T1 + (size_t)Bb*256*4; // t2 max  B*256 f32 (atomic, zero-init)
static constexpr size_t ZERO_BYTES = (OFF_T2 + (size_t)Bb*256*4) - OFF_MASK;
static constexpr size_t OFF_INT  = alup(OFF_T2 + (size_t)Bb*256*4);   // inT ws B*36 f32
static constexpr size_t OFF_FET  = alup(OFF_INT + (size_t)Bb*36*4);   // feT ws B*4096 f32
static constexpr size_t OFF_XT    = alup(OFF_FET + (size_t)Bb*4096*4);      // [6][16384]
static constexpr size_t OFF_HW    = alup(OFF_XT + (size_t)6*NPTS*4);        // [64][16384]
static constexpr size_t OFF_BUF64 = alup(OFF_HW + (size_t)64*NPTS*4);       // a1/b1/hf  [64][16384]
static constexpr size_t OFF_BUF128= alup(OFF_BUF64 + (size_t)64*NPTS*4);    // a2/b2/c1  [128][16384]
static constexpr size_t OFF_FINAL = alup(OFF_BUF128 + (size_t)128*NPTS*4);  // final (pm) [16384][256]

// ---------------- DPP helpers ----------------
// full-wave u32 max; result valid in lane 63
__device__ __forceinline__ unsigned wave_red_umax(unsigned v)
{
#define DPP_STEP(ctrl) { unsigned t = (unsigned)__builtin_amdgcn_update_dpp((int)v, (int)v, ctrl, 0xF, 0xF, false); v = (t > v) ? t : v; }
    DPP_STEP(0x111)  // row_shr:1
    DPP_STEP(0x112)  // row_shr:2
    DPP_STEP(0x114)  // row_shr:4
    DPP_STEP(0x118)  // row_shr:8
    DPP_STEP(0x142)  // row_bcast:15
    DPP_STEP(0x143)  // row_bcast:31
#undef DPP_STEP
    return v;
}

// one DPP level of f64 max (positive doubles => u64-order compare).
// ctrl must be a compile-time constant -> template parameter.
template<int CTRL>
__device__ __forceinline__ double dpp_max_f64(double v)
{
    int lo = __double2loint(v), hi = __double2hiint(v);
    int tlo = __builtin_amdgcn_update_dpp(lo, lo, CTRL, 0xF, 0xF, false);
    int thi = __builtin_amdgcn_update_dpp(hi, hi, CTRL, 0xF, 0xF, false);
    return fmax(v, __hiloint2double(thi, tlo));
}

// ---------------- FPS (+ fused xpose blocks) ----------------
// blocks 0..3: 1 block per batch, 256 threads (4 waves), 16 points/thread.
// Exact np math. Per step: dist update (6 ops/pt) + f64-key fold (4 accs + tree),
// 6 DPP f64 levels, lane63 -> LDS, barrier, 2x ds_read_b128 + 3 f64max,
// coord broadcast from LDS float4 table.
// blocks 4..: x -> channel-major transpose (independent work, overlapped).
__global__ __launch_bounds__(256) void fps_kernel(const float* __restrict__ points,
                                                  float* __restrict__ out_cent,
                                                  const float* __restrict__ x,
                                                  float* __restrict__ xT)
{
    if (blockIdx.x >= Bb) {
        int id = (blockIdx.x - Bb) * 256 + threadIdx.x;   // over 6*16384
        if (id < Ff * NPTS) {
            int ch = id >> 14;
            int g  = id & (NPTS-1);
            xT[id] = x[(size_t)g * Ff + ch];
        }
        return;
    }

    int b = blockIdx.x;
    const float* P = points + (size_t)b * Np * 3;
    int tid  = threadIdx.x;
    int lane = tid & 63;
    int wave = tid >> 6;

    __shared__ float4 sc[Np];                    // 64 KB coord table
    __shared__ __align__(16) double swin[2][4];  // per-wave winner keys

    float px[16], py[16], pz[16], dist[16];
    int ilo[16];
#pragma unroll
    for (int j = 0; j < 16; ++j) {
        int p = tid + (j << 8);
        float xx = P[p*3+0], yy = P[p*3+1], zz = P[p*3+2];
        px[j] = xx; py[j] = yy; pz[j] = zz;
        dist[j] = 1000000000.0f;
        ilo[j] = ~p;
        sc[p] = make_float4(xx, yy, zz, 0.f);
    }
    __syncthreads();

    float cx = sc[0].x, cy = sc[0].y, cz = sc[0].z;
    if (tid == 0) {
        out_cent[((size_t)b*NC + 0)*3 + 0] = cx;
        out_cent[((size_t)b*NC + 0)*3 + 1] = cy;
        out_cent[((size_t)b*NC + 0)*3 + 2] = cz;
    }

    for (int s = 1; s < NC; ++s) {
        double k0 = -1.0, k1 = -1.0, k2 = -1.0, k3 = -1.0;
#pragma unroll
        for (int j = 0; j < 16; ++j) {
            float dx = __fsub_rn(px[j], cx);
            float dy = __fsub_rn(py[j], cy);
            float dz = __fsub_rn(pz[j], cz);
            float d  = __fadd_rn(__fadd_rn(__fmul_rn(dx,dx), __fmul_rn(dy,dy)), __fmul_rn(dz,dz));
            float nd = fminf(dist[j], d);
            dist[j] = nd;
            double kj = __hiloint2double(__float_as_int(nd), ilo[j]);
            if      ((j & 3) == 0) k0 = fmax(k0, kj);
            else if ((j & 3) == 1) k1 = fmax(k1, kj);
            else if ((j & 3) == 2) k2 = fmax(k2, kj);
            else                   k3 = fmax(k3, kj);
        }
        double key = fmax(fmax(k0, k1), fmax(k2, k3));
        key = dpp_max_f64<0x111>(key);  // row_shr:1
        key = dpp_max_f64<0x112>(key);  // row_shr:2
        key = dpp_max_f64<0x114>(key);  // row_shr:4
        key = dpp_max_f64<0x118>(key);  // row_shr:8
        key = dpp_max_f64<0x142>(key);  // row_bcast:15
        key = dpp_max_f64<0x143>(key);  // row_bcast:31
        if (lane == 63) swin[s & 1][wave] = key;
        __syncthreads();

        const double2* sw = (const double2*)&swin[s & 1][0];
        double2 p01 = sw[0], p23 = sw[1];
        double kk = fmax(fmax(p01.x, p01.y), fmax(p23.x, p23.y));
        int widx = ~__double2loint(kk);

        float4 c = sc[widx];
        cx = c.x; cy = c.y; cz = c.z;
        if (tid == 0) {
            out_cent[((size_t)b*NC + s)*3 + 0] = cx;
            out_cent[((size_t)b*NC + s)*3 + 1] = cy;
            out_cent[((size_t)b*NC + s)*3 + 2] = cz;
        }
    }
}

// ---------------- ball query + g_xyz + mask ----------------
__global__ __launch_bounds__(256) void ballq_kernel(const float* __restrict__ points,
                                                    const float* __restrict__ cent,
                                                    int* __restrict__ gidx,
                                                    int* __restrict__ mask,
                                                    float* __restrict__ out_gxyz)
{
    int gtid = blockIdx.x * 256 + threadIdx.x;
    int wid  = gtid >> 6;          // b*1024 + c
    int lane = threadIdx.x & 63;
    int b = wid >> 10, c = wid & 1023;
    const float* P = points + (size_t)b * Np * 3;
    float cx = cent[((size_t)b*NC + c)*3 + 0];
    float cy = cent[((size_t)b*NC + c)*3 + 1];
    float cz = cent[((size_t)b*NC + c)*3 + 2];

    __shared__ int sidx[4][NSAMP];
    int* my = sidx[threadIdx.x >> 6];

    int count = 0;
    for (int base = 0; base < Np; base += 64) {
        int p = base + lane;
        float dx = __fsub_rn(cx, P[p*3+0]);
        float dy = __fsub_rn(cy, P[p*3+1]);
        float dz = __fsub_rn(cz, P[p*3+2]);
        float d  = __fadd_rn(__fadd_rn(__fmul_rn(dx,dx), __fmul_rn(dy,dy)), __fmul_rn(dz,dz));
        bool inr = !(d > R2);
        unsigned long long mball = __ballot(inr);
        int before = __popcll(mball & ((1ull << lane) - 1ull));
        int pos = count + before;
        if (inr && pos < NSAMP) my[pos] = p;
        count += (int)__popcll(mball);
        if (count >= NSAMP) break;
    }
    __syncthreads();
    int total = count < NSAMP ? count : NSAMP;
    int first = my[0];
    int myi = (lane < total) ? my[lane] : first;
    gidx[(size_t)wid * NSAMP + lane] = myi;
    mask[(size_t)b * Np + myi] = 1;
    float qx = P[myi*3+0], qy = P[myi*3+1], qz = P[myi*3+2];
    out_gxyz[(((size_t)b*3 + 0)*NC + c)*NSAMP + lane] = __fsub_rn(qx, cx);
    out_gxyz[(((size_t)b*3 + 1)*NC + c)*NSAMP + lane] = __fsub_rn(qy, cy);
    out_gxyz[(((size_t)b*3 + 2)*NC + c)*NSAMP + lane] = __fsub_rn(qz, cz);
}

// ---------------- register-blocked layer: out = [relu](in @ W) ----------------
// in: [K][16384] channel-major. W: [K][N] (row-major; per-batch stride K*N if BW).
// block = 256 threads; tile = 1024 points x NT outputs; 4 points/thread.
// grid = (16, N/NT). Weight tile staged in LDS, read as float4 broadcasts.
// TM mode (trunk layer-3): no output write; masked relu-max per channel ->
// global atomicMax into tmax[b*256 + o]. Requires N==256.
template<int K, int N, int NT, bool RELU, bool PM, bool BW, bool TM>
__global__ __launch_bounds__(256) void layer2_k(const float* __restrict__ in,
                                                const float* __restrict__ W,
                                                float* __restrict__ out,
                                                const int* __restrict__ mask,
                                                unsigned* __restrict__ tmax)
{
    static_assert(NT % 4 == 0, "NT multiple of 4");
    int tid = threadIdx.x;
    int g0  = blockIdx.x * 1024 + tid;
    int o0  = blockIdx.y * NT;
    const float* Wb = W;
    if (BW) Wb += (size_t)(blockIdx.x >> 2) * K * N;

    __shared__ __align__(16) float ws[K * NT];
    for (int i = tid; i < K * NT; i += 256)
        ws[i] = Wb[(size_t)(i / NT) * N + o0 + (i % NT)];
    __syncthreads();

    float acc[4][NT];
#pragma unroll
    for (int mi = 0; mi < 4; ++mi)
#pragma unroll
        for (int oo = 0; oo < NT; ++oo) acc[mi][oo] = 0.f;

#pragma unroll 2
    for (int k = 0; k < K; ++k) {
        float a0 = in[(size_t)k * NPTS + g0];
        float a1 = in[(size_t)k * NPTS + g0 + 256];
        float a2 = in[(size_t)k * NPTS + g0 + 512];
        float a3 = in[(size_t)k * NPTS + g0 + 768];
        const float4* wr = (const float4*)&ws[k * NT];
#pragma unroll
        for (int q = 0; q < NT/4; ++q) {
            float4 w = wr[q];
            acc[0][4*q+0] += a0 * w.x;  acc[0][4*q+1] += a0 * w.y;
            acc[0][4*q+2] += a0 * w.z;  acc[0][4*q+3] += a0 * w.w;
            acc[1][4*q+0] += a1 * w.x;  acc[1][4*q+1] += a1 * w.y;
            acc[1][4*q+2] += a1 * w.z;  acc[1][4*q+3] += a1 * w.w;
            acc[2][4*q+0] += a2 * w.x;  acc[2][4*q+1] += a2 * w.y;
            acc[2][4*q+2] += a2 * w.z;  acc[2][4*q+3] += a2 * w.w;
            acc[3][4*q+0] += a3 * w.x;  acc[3][4*q+1] += a3 * w.y;
            acc[3][4*q+2] += a3 * w.z;  acc[3][4*q+3] += a3 * w.w;
        }
    }

    if (TM) {
        float tmv[NT];
#pragma unroll
        for (int oo = 0; oo < NT; ++oo) tmv[oo] = 0.f;
#pragma unroll
        for (int mi = 0; mi < 4; ++mi) {
            bool pres = mask[g0 + mi * 256] != 0;
#pragma unroll
            for (int oo = 0; oo < NT; ++oo) {
                float v = pres ? fmaxf(acc[mi][oo], 0.f) : 0.f;
                tmv[oo] = fmaxf(tmv[oo], v);
            }
        }
        int b = g0 >> 12;
        int lane = tid & 63;
#pragma unroll
        for (int oo = 0; oo < NT; ++oo) {
            unsigned r = wave_red_umax(__float_as_uint(tmv[oo]));
            if (lane == 63)
                atomicMax(&tmax[(b << 8) + o0 + oo], r);
        }
        return;
    }

#pragma unroll
    for (int mi = 0; mi < 4; ++mi) {
        int g = g0 + mi * 256;
#pragma unroll
        for (int oo = 0; oo < NT; ++oo) {
            float v = acc[mi][oo];
            if (RELU) v = fmaxf(v, 0.f);
            if (PM) out[(size_t)g * N + o0 + oo] = v;
            else    out[(size_t)(o0 + oo) * NPTS + g] = v;
        }
    }
}

// ---------------- h = relu((x @ inT) @ w1) ----------------
__global__ __launch_bounds__(256) void l_h_kernel(const float* __restrict__ xT,
                                                  const float* __restrict__ inT,
                                                  const float* __restrict__ w1,
                                                  float* __restrict__ hw)
{
    int g = blockIdx.x * 256 + threadIdx.x;
    int b = g >> 12;
    float v[6];
#pragma unroll
    for (int c = 0; c < 6; ++c) v[c] = xT[(size_t)c * NPTS + g];
    float t[6];
#pragma unroll
    for (int o = 0; o < 6; ++o) {
        float acc = 0.f;
#pragma unroll
        for (int c = 0; c < 6; ++c) acc += v[c] * inT[b*36 + c*6 + o];
        t[o] = acc;
    }
#pragma unroll 8
    for (int j = 0; j < 64; ++j) {
        float acc = 0.f;
#pragma unroll
        for (int o = 0; o < 6; ++o) acc += t[o] * w1[o*64 + j];
        hw[(size_t)j * NPTS + g] = fmaxf(acc, 0.f);
    }
}

// ---------------- tnet heads ----------------
__global__ __launch_bounds__(256) void head1_kernel(const float* __restrict__ t1,
                                                    const float* __restrict__ f1,  // 256x128
                                                    const float* __restrict__ f2,  // 128x36
                                                    float* __restrict__ outT, float* __restrict__ wsT)
{
    int b = blockIdx.x, t = threadIdx.x;
    __shared__ float tv[256], u[128];
    tv[t] = t1[(size_t)b*256 + t];
    __syncthreads();
    if (t < 128) {
        float acc = 0.f;
        for (int k = 0; k < 256; ++k) acc += tv[k] * f1[(size_t)k*128 + t];
        u[t] = fmaxf(acc, 0.f);
    }
    __syncthreads();
    if (t < 36) {
        float acc = 0.f;
        for (int k = 0; k < 128; ++k) acc += u[k] * f2[(size_t)k*36 + t];
        if (t / 6 == t % 6) acc += 1.0f;
        outT[b*36 + t] = acc;
        wsT[b*36 + t]  = acc;
    }
}

// grid (Bb, 16): each block computes u[128] (redundant, tiny) then 256 j-outputs.
__global__ __launch_bounds__(256) void head2_kernel(const float* __restrict__ t2,
                                                    const float* __restrict__ f1,  // 256x128
                                                    const float* __restrict__ f2,  // 128x4096
                                                    float* __restrict__ outT, float* __restrict__ wsT)
{
    int b = blockIdx.x, t = threadIdx.x;
    __shared__ float tv[256], u[128];
    tv[t] = t2[(size_t)b*256 + t];
    __syncthreads();
    if (t < 128) {
        float acc = 0.f;
        for (int k = 0; k < 256; ++k) acc += tv[k] * f1[(size_t)k*128 + t];
        u[t] = fmaxf(acc, 0.f);
    }
    __syncthreads();
    int j = blockIdx.y * 256 + t;
    float acc = 0.f;
#pragma unroll 8
    for (int k = 0; k < 128; ++k) acc += u[k] * f2[(size_t)k*4096 + j];
    if (j / 64 == j % 64) acc += 1.0f;
    outT[(size_t)b*4096 + j] = acc;
    wsT[(size_t)b*4096 + j]  = acc;
}

// ---------------- feats: grouped gather-max + transpose ----------------
__global__ __launch_bounds__(256) void feats_kernel(const float* __restrict__ fin,   // [16384][256] pm
                                                    const int* __restrict__ gidx,
                                                    float* __restrict__ out)         // (B,256,1024)
{
    int bid = blockIdx.x;            // b*1024 + c
    int b = bid >> 10, c = bid & 1023;
    int o = threadIdx.x;
    __shared__ int sid[NSAMP];
    if (o < NSAMP) sid[o] = gidx[(size_t)bid * NSAMP + o];
    __syncthreads();
    const float* fb = fin + (size_t)b * Np * 256;
    float m = -1e30f;
    for (int s = 0; s < NSAMP; ++s)
        m = fmaxf(m, fb[(size_t)sid[s] * 256 + o]);
    out[((size_t)b*256 + o)*NC + c] = m;
}

// ---------------- launch ----------------
extern "C" void kernel_launch(void* const* d_in, const int* in_sizes, int n_in,
                              void* d_out, int out_size, void* d_ws, size_t ws_size,
                              hipStream_t stream)
{
    const float* x      = (const float*)d_in[0];
    const float* points = (const float*)d_in[1];
    const float* t1_w1  = (const float*)d_in[2];
    const float* t1_w2  = (const float*)d_in[3];
    const float* t1_w3  = (const float*)d_in[4];
    const float* t1_f1  = (const float*)d_in[5];
    const float* t1_f2  = (const float*)d_in[6];
    const float* t2_w1  = (const float*)d_in[7];
    const float* t2_w2  = (const float*)d_in[8];
    const float* t2_w3  = (const float*)d_in[9];
    const float* t2_f1  = (const float*)d_in[10];
    const float* t2_f2  = (const float*)d_in[11];
    const float* w1     = (const float*)d_in[12];
    const float* w2     = (const float*)d_in[13];
    const float* w3     = (const float*)d_in[14];

    float* out = (float*)d_out;
    float* out_cent  = out;                 // (4,1024,3)
    float* out_gxyz  = out + 12288;         // (4,3,1024,64)
    float* out_feats = out + 798720;        // (4,256,1024)
    float* out_inT   = out + 1847296;       // (4,6,6)
    float* out_feT   = out + 1847440;       // (4,64,64)

    char* ws = (char*)d_ws;
    int*      gidx  = (int*)(ws + OFF_GIDX);
    int*      mask  = (int*)(ws + OFF_MASK);
    unsigned* t1max = (unsigned*)(ws + OFF_T1);
    unsigned* t2max = (unsigned*)(ws + OFF_T2);
    float*    wsInT = (float*)(ws + OFF_INT);
    float*    wsFeT = (float*)(ws + OFF_FET);
    float*    xT    = (float*)(ws + OFF_XT);
    float*    hw    = (float*)(ws + OFF_HW);
    float*    buf64 = (float*)(ws + OFF_BUF64);
    float*    buf128= (float*)(ws + OFF_BUF128);
    float*    fin   = (float*)(ws + OFF_FINAL);

    // zero mask + t1max + t2max (contiguous)
    (void)hipMemsetAsync(ws + OFF_MASK, 0, ZERO_BYTES, stream);

    // fps (blocks 0..3) + fused xpose (blocks 4..387)
    fps_kernel<<<Bb + (Ff*NPTS + 255)/256, 256, 0, stream>>>(points, out_cent, x, xT);
    ballq_kernel<<<(Bb*NC)/4, 256, 0, stream>>>(points, out_cent, gidx, mask, out_gxyz);

    // tnet1 trunk (layer3 fused with masked max)
    layer2_k<6,  64, 16, true,  false, false, false><<<dim3(16, 4), 256, 0, stream>>>(xT,    t1_w1, buf64,  nullptr, nullptr);
    layer2_k<64, 128,16, true,  false, false, false><<<dim3(16, 8), 256, 0, stream>>>(buf64, t1_w2, buf128, nullptr, nullptr);
    layer2_k<128,256,16, false, false, false, true ><<<dim3(16,16), 256, 0, stream>>>(buf128,t1_w3, nullptr, mask, t1max);
    head1_kernel<<<Bb, 256, 0, stream>>>((const float*)t1max, t1_f1, t1_f2, out_inT, wsInT);
    // h = relu((x @ inT) @ w1)
    l_h_kernel<<<NPTS/256, 256, 0, stream>>>(xT, wsInT, w1, hw);
    // tnet2 trunk (layer3 fused with masked max)
    layer2_k<64, 64, 16, true,  false, false, false><<<dim3(16, 4), 256, 0, stream>>>(hw,    t2_w1, buf64,  nullptr, nullptr);
    layer2_k<64, 128,16, true,  false, false, false><<<dim3(16, 8), 256, 0, stream>>>(buf64, t2_w2, buf128, nullptr, nullptr);
    layer2_k<128,256,16, false, false, false, true ><<<dim3(16,16), 256, 0, stream>>>(buf128,t2_w3, nullptr, mask, t2max);
    head2_kernel<<<dim3(Bb,16), 256, 0, stream>>>((const float*)t2max, t2_f1, t2_f2, out_feT, wsFeT);
    // hf = h @ feT (per-batch weights)
    layer2_k<64, 64, 16, false, false, true,  false><<<dim3(16, 4), 256, 0, stream>>>(hw,    wsFeT, buf64,  nullptr, nullptr);
    // c1 = relu(hf @ w2)
    layer2_k<64, 128,16, true,  false, false, false><<<dim3(16, 8), 256, 0, stream>>>(buf64, w2,    buf128, nullptr, nullptr);
    // final = relu(c1 @ w3), point-major
    layer2_k<128,256,16, true,  true,  false, false><<<dim3(16,16), 256, 0, stream>>>(buf128,w3,    fin,    nullptr, nullptr);
    feats_kernel<<<Bb*NC, 256, 0, stream>>>(fin, gidx, out_feats);

    (void)in_sizes; (void)n_in; (void)out_size; (void)ws_size;
}